// Round 1
// baseline (971.661 us; speedup 1.0000x reference)
//
#include <hip/hip_runtime.h>
#include <hip/hip_bf16.h>
#include <math.h>

// SDGCN fused kernel, fp32 baseline.
// Per (b,t): scores = X X^T, row-softmax, Ag = A*(softmax/8 + 1e-8),
// H = Ag @ X, out = LN(relu(H @ W^T))*gamma+beta + X.
// NOTE: the 1e-8 * (A@X) term contributes ~1e-6 absolute to the final
// output (threshold 1.6e-1) and is dropped.

constexpr int kBT = 48;   // B*T
constexpr int kN  = 1024;
constexpr int kD  = 64;
constexpr int kRB = 32;   // rows per block
constexpr int kMT = 64;   // m-tile (columns of scores per iteration)
constexpr int kS  = 68;   // LDS row stride in floats (pad: 16B-aligned, spreads banks)

__global__ __launch_bounds__(256)
void sdgcn_fused(const float* __restrict__ X, const float* __restrict__ A,
                 const float* __restrict__ W, const float* __restrict__ gamma,
                 const float* __restrict__ beta, float* __restrict__ out)
{
    __shared__ __align__(16) float Ks[kMT][kS];  // X m-tile; reused for W^T in epilogue
    __shared__ __align__(16) float Ps[kRB][kS];  // p*A tile; reused for H in epilogue

    const int bid = blockIdx.x;
    const int bt  = bid >> 5;          // 32 row-blocks per (b,t)
    const int rb  = bid & 31;
    const int t   = threadIdx.x;
    const int r   = t >> 3;            // 0..31  (row within slab)
    const int c8  = t & 7;             // 0..7   (8 threads cooperate per row)
    const int d0  = c8 * 8;            // this thread's 8-wide d/i slice

    const float* __restrict__ Xbt = X + (size_t)bt * kN * kD;
    const int grow = rb * kRB + r;     // global row index n

    // ---- Q row into registers (statically indexed only) ----
    float q[kD];
    {
        const float4* qs = reinterpret_cast<const float4*>(Xbt + grow * kD);
#pragma unroll
        for (int i = 0; i < kD / 4; ++i) {
            float4 v = qs[i];
            q[4*i+0] = v.x; q[4*i+1] = v.y; q[4*i+2] = v.z; q[4*i+3] = v.w;
        }
    }

    float o[8];
#pragma unroll
    for (int k = 0; k < 8; ++k) o[k] = 0.f;
    float rowmax = -3.0e38f;
    float Z = 0.f;

    // ================= main loop over m-tiles =================
    for (int m0 = 0; m0 < kN; m0 += kMT) {
        __syncthreads();   // prior tile's reads of Ks/Ps done
        // stage K tile: 64 rows x 64 floats, coalesced float4
#pragma unroll
        for (int k = 0; k < 4; ++k) {
            int idx = t + k * 256;            // 0..1023 float4s
            int mm  = idx >> 4;               // 16 float4 per row
            int dd  = (idx & 15) * 4;
            float4 v = *reinterpret_cast<const float4*>(Xbt + (m0 + mm) * kD + dd);
            *reinterpret_cast<float4*>(&Ks[mm][dd]) = v;
        }
        __syncthreads();

        // ---- scores: s[j] = q . K[c8 + 8j] ----
        float s[8];
#pragma unroll
        for (int j = 0; j < 8; ++j) s[j] = 0.f;
#pragma unroll
        for (int d4 = 0; d4 < 16; ++d4) {
            const float q0 = q[4*d4+0], q1 = q[4*d4+1], q2 = q[4*d4+2], q3 = q[4*d4+3];
#pragma unroll
            for (int j = 0; j < 8; ++j) {
                float4 k4 = *reinterpret_cast<const float4*>(&Ks[c8 + 8*j][4*d4]);
                s[j] = fmaf(q0, k4.x, s[j]);
                s[j] = fmaf(q1, k4.y, s[j]);
                s[j] = fmaf(q2, k4.z, s[j]);
                s[j] = fmaf(q3, k4.w, s[j]);
            }
        }

        // ---- online softmax update (per row; 8 lanes per row) ----
        float tm = s[0];
#pragma unroll
        for (int j = 1; j < 8; ++j) tm = fmaxf(tm, s[j]);
#pragma unroll
        for (int off = 1; off < 8; off <<= 1) tm = fmaxf(tm, __shfl_xor(tm, off, 64));

        float nm    = fmaxf(rowmax, tm);
        float scale = expf(rowmax - nm);
        float p[8];
        float zt = 0.f;
#pragma unroll
        for (int j = 0; j < 8; ++j) { p[j] = expf(s[j] - nm); zt += p[j]; }
#pragma unroll
        for (int off = 1; off < 8; off <<= 1) zt += __shfl_xor(zt, off, 64);
        Z = Z * scale + zt;
        rowmax = nm;
#pragma unroll
        for (int k = 0; k < 8; ++k) o[k] *= scale;

        // ---- PA = p * A into LDS ----
        {
            const float* __restrict__ Arow = A + (size_t)grow * kN + m0;
#pragma unroll
            for (int j = 0; j < 8; ++j)
                Ps[r][c8 + 8*j] = p[j] * Arow[c8 + 8*j];
        }
        __syncthreads();

        // ---- O += PA[r][m] * K[m][d0..d0+7] ----
#pragma unroll 8
        for (int m = 0; m < kMT; ++m) {
            float pa = Ps[r][m];
            float4 xa = *reinterpret_cast<const float4*>(&Ks[m][d0]);
            float4 xb = *reinterpret_cast<const float4*>(&Ks[m][d0 + 4]);
            o[0] = fmaf(pa, xa.x, o[0]);
            o[1] = fmaf(pa, xa.y, o[1]);
            o[2] = fmaf(pa, xa.z, o[2]);
            o[3] = fmaf(pa, xa.w, o[3]);
            o[4] = fmaf(pa, xb.x, o[4]);
            o[5] = fmaf(pa, xb.y, o[5]);
            o[6] = fmaf(pa, xb.z, o[6]);
            o[7] = fmaf(pa, xb.w, o[7]);
        }
    }

    // ================= epilogue =================
    const float inv = 1.f / (8.f * Z);   // sqrt(64) = 8

    __syncthreads();                     // main-loop reads of Ps/Ks done
    // H row into Ps
#pragma unroll
    for (int k = 0; k < 8; ++k) Ps[r][d0 + k] = o[k] * inv;
    // W^T into Ks: Ks[j][i] = W[i*64 + j] (coalesced global read)
#pragma unroll
    for (int k = 0; k < 16; ++k) {
        int idx = t + k * 256;           // 0..4095
        int i = idx >> 6, j = idx & 63;
        Ks[j][i] = W[idx];
    }
    __syncthreads();

    // out_i = relu(sum_j H[j] * W[i][j]), i in [d0, d0+8)
    float acc[8];
#pragma unroll
    for (int k = 0; k < 8; ++k) acc[k] = 0.f;
#pragma unroll 8
    for (int j = 0; j < kD; ++j) {
        float hv = Ps[r][j];
        float4 wa = *reinterpret_cast<const float4*>(&Ks[j][d0]);
        float4 wb = *reinterpret_cast<const float4*>(&Ks[j][d0 + 4]);
        acc[0] = fmaf(hv, wa.x, acc[0]);
        acc[1] = fmaf(hv, wa.y, acc[1]);
        acc[2] = fmaf(hv, wa.z, acc[2]);
        acc[3] = fmaf(hv, wa.w, acc[3]);
        acc[4] = fmaf(hv, wb.x, acc[4]);
        acc[5] = fmaf(hv, wb.y, acc[5]);
        acc[6] = fmaf(hv, wb.z, acc[6]);
        acc[7] = fmaf(hv, wb.w, acc[7]);
    }

    // relu + LayerNorm (var = E[x^2] - mu^2, ddof=0 like jnp.var)
    float sum = 0.f, sq = 0.f;
#pragma unroll
    for (int k = 0; k < 8; ++k) {
        acc[k] = fmaxf(acc[k], 0.f);
        sum += acc[k];
        sq = fmaf(acc[k], acc[k], sq);
    }
#pragma unroll
    for (int off = 1; off < 8; off <<= 1) {
        sum += __shfl_xor(sum, off, 64);
        sq  += __shfl_xor(sq,  off, 64);
    }
    const float mu   = sum * (1.f / 64.f);
    const float var  = sq * (1.f / 64.f) - mu * mu;
    const float rstd = rsqrtf(var + 1e-5f);

    float4 g0 = *reinterpret_cast<const float4*>(gamma + d0);
    float4 g1 = *reinterpret_cast<const float4*>(gamma + d0 + 4);
    float4 b0 = *reinterpret_cast<const float4*>(beta + d0);
    float4 b1 = *reinterpret_cast<const float4*>(beta + d0 + 4);
    // residual: reload X slice (L1-hot) to avoid runtime-indexing q[] (scratch)
    float4 x0 = *reinterpret_cast<const float4*>(Xbt + grow * kD + d0);
    float4 x1 = *reinterpret_cast<const float4*>(Xbt + grow * kD + d0 + 4);

    float4 r0, r1;
    r0.x = (acc[0] - mu) * rstd * g0.x + b0.x + x0.x;
    r0.y = (acc[1] - mu) * rstd * g0.y + b0.y + x0.y;
    r0.z = (acc[2] - mu) * rstd * g0.z + b0.z + x0.z;
    r0.w = (acc[3] - mu) * rstd * g0.w + b0.w + x0.w;
    r1.x = (acc[4] - mu) * rstd * g1.x + b1.x + x1.x;
    r1.y = (acc[5] - mu) * rstd * g1.y + b1.y + x1.y;
    r1.z = (acc[6] - mu) * rstd * g1.z + b1.z + x1.z;
    r1.w = (acc[7] - mu) * rstd * g1.w + b1.w + x1.w;

    float4* op = reinterpret_cast<float4*>(out + (size_t)bt * kN * kD + grow * kD + d0);
    op[0] = r0;
    op[1] = r1;
}

extern "C" void kernel_launch(void* const* d_in, const int* in_sizes, int n_in,
                              void* d_out, int out_size, void* d_ws, size_t ws_size,
                              hipStream_t stream) {
    const float* X     = (const float*)d_in[0];
    const float* A     = (const float*)d_in[1];
    const float* W     = (const float*)d_in[2];
    const float* gamma = (const float*)d_in[3];
    const float* beta  = (const float*)d_in[4];
    float* out = (float*)d_out;

    dim3 grid(kBT * (kN / kRB));   // 48 * 32 = 1536 blocks
    sdgcn_fused<<<grid, 256, 0, stream>>>(X, A, W, gamma, beta, out);
}

// Round 2
// 91.046 us; speedup vs baseline: 10.6722x; 10.6722x over previous
//
#include <hip/hip_runtime.h>
#include <hip/hip_bf16.h>
#include <math.h>

// SDGCN fused, split-bf16 MFMA version.
// Per (b,t): S = X X^T (swapped-layout MFMA, fp32 via bf16 hi/lo x3 terms),
// online softmax (running m, Z), P = A .* exp(S-m), O += P V (MFMA, hi/lo),
// H = O/(8 Z), lin = H W^T (MFMA), out = LN(relu(lin))*gamma+beta + X.
// The 1e-8*(A@X) term contributes ~1e-6 abs -> dropped.
//
// mfma_f32_16x16x32_bf16 layouts (m89/m92-verified):
//   A-frag: lane l holds A[l&15][(l>>4)*8+e]   (8 contiguous k)
//   B-frag: lane l holds B[(l>>4)*8+e][l&15]
//   C/D:    lane l, reg r holds C[(l>>4)*4+r][l&15]

typedef short bf16x8 __attribute__((ext_vector_type(8)));
typedef float f32x4  __attribute__((ext_vector_type(4)));

constexpr int kN  = 1024;
constexpr int kD  = 64;
constexpr int kKS = 72;   // K LDS row stride (shorts) = 144B (16B-aligned, 2-way banks)
constexpr int kVS = 40;   // Vt LDS row stride (shorts) = 80B
constexpr int kHS = 68;   // H exchange row stride (floats) = 272B

#define MFMA_BF16(a, b, c) __builtin_amdgcn_mfma_f32_16x16x32_bf16((a), (b), (c), 0, 0, 0)

// truncation split: v = hi + lo with hi,lo bf16; product error ~2^-17
__device__ __forceinline__ void splitv(float v, short& h, short& l) {
  unsigned u = __float_as_uint(v);
  h = (short)(u >> 16);
  float hf = __uint_as_float(u & 0xFFFF0000u);
  l = (short)(__float_as_uint(v - hf) >> 16);
}

__global__ __launch_bounds__(256)
void sdgcn_mfma(const float* __restrict__ X, const float* __restrict__ A,
                const float* __restrict__ W, const float* __restrict__ gamma,
                const float* __restrict__ beta, float* __restrict__ out)
{
  __shared__ __align__(16) short Kh[32 * kKS], Kl[32 * kKS];   // K tile row-major (hi/lo)
  __shared__ __align__(16) short Vth[64 * kVS], Vtl[64 * kVS]; // V tile transposed [d][m]
  __shared__ __align__(16) float Hs[4][16 * kHS];              // per-wave H exchange

  const int t    = threadIdx.x;
  const int wave = t >> 6;
  const int lane = t & 63;
  const int g    = lane >> 4;   // 0..3
  const int ql   = lane & 15;   // 0..15
  const int bt   = blockIdx.x >> 4;
  const int qt   = blockIdx.x & 15;
  const int qbase = qt * 64 + wave * 16;    // this wave's 16 q-rows
  const float* __restrict__ Xbt = X + (size_t)bt * kN * kD;

  // ---- Q fragments (B-operand of swapped QK): lane holds Q[qbase+ql][kk*32+g*8+e]
  bf16x8 qh[2], qlo[2];
#pragma unroll
  for (int kk = 0; kk < 2; ++kk) {
    const float* qp = Xbt + (size_t)(qbase + ql) * kD + kk * 32 + g * 8;
    float4 v0 = *(const float4*)qp;
    float4 v1 = *(const float4*)(qp + 4);
    float v[8] = {v0.x, v0.y, v0.z, v0.w, v1.x, v1.y, v1.z, v1.w};
#pragma unroll
    for (int e = 0; e < 8; ++e) { short hh, ll; splitv(v[e], hh, ll); qh[kk][e] = hh; qlo[kk][e] = ll; }
  }

  f32x4 o[4];   // O accumulator: o[c][r] = O[q=4g+r][d=16c+ql]
#pragma unroll
  for (int c = 0; c < 4; ++c) o[c] = {0.f, 0.f, 0.f, 0.f};
  float mrun = -INFINITY, Z = 0.f;

  const int smm  = t >> 3;              // staging row 0..31
  const int sd8  = (t & 7) * 8;         // staging d 0..56
  const int sxor = ((sd8 >> 3) & 3) << 3;  // Vt column XOR-swizzle (short units)

  for (int ks = 0; ks < 32; ++ks) {
    const int kbase = ks * 32;
    __syncthreads();  // previous step's LDS reads complete
    {
      const float* sp = Xbt + (size_t)(kbase + smm) * kD + sd8;
      float4 v0 = *(const float4*)sp;
      float4 v1 = *(const float4*)(sp + 4);
      float v[8] = {v0.x, v0.y, v0.z, v0.w, v1.x, v1.y, v1.z, v1.w};
      short h[8], l[8];
#pragma unroll
      for (int e = 0; e < 8; ++e) splitv(v[e], h[e], l[e]);
      bf16x8 hv, lv;
#pragma unroll
      for (int e = 0; e < 8; ++e) { hv[e] = h[e]; lv[e] = l[e]; }
      *(bf16x8*)&Kh[smm * kKS + sd8] = hv;
      *(bf16x8*)&Kl[smm * kKS + sd8] = lv;
      const int col = smm ^ sxor;  // swizzled m-column
#pragma unroll
      for (int e = 0; e < 8; ++e) {
        Vth[(sd8 + e) * kVS + col] = h[e];
        Vtl[(sd8 + e) * kVS + col] = l[e];
      }
    }
    __syncthreads();

    // prefetch A gate values (hidden under QK): A[qbase+ql][kbase + 8g + e]
    const float* Ap = A + (size_t)(qbase + ql) * kN + kbase + g * 8;
    float4 ag0 = *(const float4*)Ap;
    float4 ag1 = *(const float4*)(Ap + 4);

    // ---- QK^T swapped: C[k][q]; lane holds S[q=ql][k = 16*tt + 4g + r]
    f32x4 s[2];
#pragma unroll
    for (int tt = 0; tt < 2; ++tt) {
      const int krow = tt * 16 + ql;
      bf16x8 kh0 = *(const bf16x8*)&Kh[krow * kKS + g * 8];
      bf16x8 kh1 = *(const bf16x8*)&Kh[krow * kKS + 32 + g * 8];
      bf16x8 kl0 = *(const bf16x8*)&Kl[krow * kKS + g * 8];
      bf16x8 kl1 = *(const bf16x8*)&Kl[krow * kKS + 32 + g * 8];
      f32x4 acc = {0.f, 0.f, 0.f, 0.f};
      acc = MFMA_BF16(kh0, qh[0],  acc);
      acc = MFMA_BF16(kh1, qh[1],  acc);
      acc = MFMA_BF16(kh0, qlo[0], acc);
      acc = MFMA_BF16(kh1, qlo[1], acc);
      acc = MFMA_BF16(kl0, qh[0],  acc);
      acc = MFMA_BF16(kl1, qh[1],  acc);
      s[tt] = acc;
    }

    // ---- online softmax (stats owned by lanes as q=ql, replicated over g)
    float sm = s[0][0];
#pragma unroll
    for (int r = 1; r < 4; ++r) sm = fmaxf(sm, s[0][r]);
#pragma unroll
    for (int r = 0; r < 4; ++r) sm = fmaxf(sm, s[1][r]);
    sm = fmaxf(sm, __shfl_xor(sm, 16, 64));
    sm = fmaxf(sm, __shfl_xor(sm, 32, 64));
    const float nm = fmaxf(mrun, sm);
    const float f  = __expf(mrun - nm);   // 0 on first iter
    float p[2][4];
    float zt = 0.f;
#pragma unroll
    for (int tt = 0; tt < 2; ++tt)
#pragma unroll
      for (int r = 0; r < 4; ++r) { p[tt][r] = __expf(s[tt][r] - nm); zt += p[tt][r]; }
    zt += __shfl_xor(zt, 16, 64);
    zt += __shfl_xor(zt, 32, 64);
    Z = Z * f + zt;
    mrun = nm;

    // rescale O: factor for q = 4g + r comes from lane (4g + r) (group 0 copy)
#pragma unroll
    for (int r = 0; r < 4; ++r) {
      const float fr = __shfl(f, ((lane >> 4) << 2) + r, 64);
#pragma unroll
      for (int c = 0; c < 4; ++c) o[c][r] *= fr;
    }

    // ---- exchange P to PV A-frag layout: lane (ql,g) wants P[q=ql][k=8g+e]
    // source: lane (ql, gs=2(g&1)+(e>>2)) tile tt=g>>1, reg r=e&3
    const int src0 = ((2 * (g & 1)) << 4) | ql;
    const int src1 = src0 + 16;
    float pa[8];
    const bool hihalf = (g >> 1) != 0;
#pragma unroll
    for (int r = 0; r < 4; ++r) {
      float a0 = __shfl(p[0][r], src0, 64);
      float a1 = __shfl(p[1][r], src0, 64);
      float b0 = __shfl(p[0][r], src1, 64);
      float b1 = __shfl(p[1][r], src1, 64);
      pa[r]     = hihalf ? a1 : a0;
      pa[r + 4] = hihalf ? b1 : b0;
    }
    // gate by A
    pa[0] *= ag0.x; pa[1] *= ag0.y; pa[2] *= ag0.z; pa[3] *= ag0.w;
    pa[4] *= ag1.x; pa[5] *= ag1.y; pa[6] *= ag1.z; pa[7] *= ag1.w;
    bf16x8 pah, pal;
#pragma unroll
    for (int e = 0; e < 8; ++e) { short hh, ll; splitv(pa[e], hh, ll); pah[e] = hh; pal[e] = ll; }

    // ---- PV: O[q][d] += P[q][k] V[k][d]
#pragma unroll
    for (int c = 0; c < 4; ++c) {
      const int d = c * 16 + ql;
      const int vcol = (8 * g) ^ ((((d >> 3) & 3)) << 3);
      bf16x8 vh = *(const bf16x8*)&Vth[d * kVS + vcol];
      bf16x8 vl = *(const bf16x8*)&Vtl[d * kVS + vcol];
      o[c] = MFMA_BF16(pah, vh, o[c]);
      o[c] = MFMA_BF16(pah, vl, o[c]);
      o[c] = MFMA_BF16(pal, vh, o[c]);
    }
  }

  // ================= epilogue =================
  // H = O / (8 Z); Z for q=4g+r from lane (4g+r)
  float invr[4];
#pragma unroll
  for (int r = 0; r < 4; ++r) {
    const float zq = __shfl(Z, ((lane >> 4) << 2) + r, 64);
    invr[r] = 1.0f / (8.0f * zq);
  }
  float* Hw = Hs[wave];
#pragma unroll
  for (int c = 0; c < 4; ++c)
#pragma unroll
    for (int r = 0; r < 4; ++r)
      Hw[(4 * g + r) * kHS + c * 16 + ql] = o[c][r] * invr[r];
  __syncthreads();

  // H A-frags: lane holds H[q=ql][kd = kk*32 + 8g + e]
  bf16x8 hh[2], hl[2];
#pragma unroll
  for (int kk = 0; kk < 2; ++kk) {
    const float* hp = &Hw[ql * kHS + kk * 32 + g * 8];
    float4 v0 = *(const float4*)hp;
    float4 v1 = *(const float4*)(hp + 4);
    float v[8] = {v0.x, v0.y, v0.z, v0.w, v1.x, v1.y, v1.z, v1.w};
#pragma unroll
    for (int e = 0; e < 8; ++e) { short a, b; splitv(v[e], a, b); hh[kk][e] = a; hl[kk][e] = b; }
  }

  // lin = H W^T per i-chunk; B-frag = W^T[kd][i] = W[i=16c+ql][kd=kk*32+8g+e]
  f32x4 lin[4];
#pragma unroll
  for (int c = 0; c < 4; ++c) {
    bf16x8 wh[2], wl[2];
#pragma unroll
    for (int kk = 0; kk < 2; ++kk) {
      const float* wp = W + (size_t)(c * 16 + ql) * kD + kk * 32 + g * 8;
      float4 v0 = *(const float4*)wp;
      float4 v1 = *(const float4*)(wp + 4);
      float v[8] = {v0.x, v0.y, v0.z, v0.w, v1.x, v1.y, v1.z, v1.w};
#pragma unroll
      for (int e = 0; e < 8; ++e) { short a, b; splitv(v[e], a, b); wh[kk][e] = a; wl[kk][e] = b; }
    }
    f32x4 acc = {0.f, 0.f, 0.f, 0.f};
    acc = MFMA_BF16(hh[0], wh[0], acc);
    acc = MFMA_BF16(hh[1], wh[1], acc);
    acc = MFMA_BF16(hh[0], wl[0], acc);
    acc = MFMA_BF16(hh[1], wl[1], acc);
    acc = MFMA_BF16(hl[0], wh[0], acc);
    acc = MFMA_BF16(hl[1], wh[1], acc);
    lin[c] = acc;
  }

  // relu + LN per q-row (row q=4g+r lives in lanes sharing g, spread over ql,c)
  float rl[4][4];
#pragma unroll
  for (int c = 0; c < 4; ++c)
#pragma unroll
    for (int r = 0; r < 4; ++r) rl[c][r] = fmaxf(lin[c][r], 0.f);

  float mu[4], rstd[4];
#pragma unroll
  for (int r = 0; r < 4; ++r) {
    float s1 = rl[0][r] + rl[1][r] + rl[2][r] + rl[3][r];
    float s2 = rl[0][r] * rl[0][r] + rl[1][r] * rl[1][r] + rl[2][r] * rl[2][r] + rl[3][r] * rl[3][r];
#pragma unroll
    for (int off = 1; off < 16; off <<= 1) {
      s1 += __shfl_xor(s1, off, 64);
      s2 += __shfl_xor(s2, off, 64);
    }
    mu[r] = s1 * (1.f / 64.f);
    const float var = s2 * (1.f / 64.f) - mu[r] * mu[r];
    rstd[r] = rsqrtf(var + 1e-5f);
  }

#pragma unroll
  for (int c = 0; c < 4; ++c) {
    const float gm = gamma[c * 16 + ql];
    const float bb = beta[c * 16 + ql];
#pragma unroll
    for (int r = 0; r < 4; ++r) {
      const int qrow = qbase + 4 * g + r;
      const size_t off = ((size_t)bt * kN + qrow) * kD + c * 16 + ql;
      out[off] = (rl[c][r] - mu[r]) * rstd[r] * gm + bb + X[off];
    }
  }
}

extern "C" void kernel_launch(void* const* d_in, const int* in_sizes, int n_in,
                              void* d_out, int out_size, void* d_ws, size_t ws_size,
                              hipStream_t stream) {
  const float* X     = (const float*)d_in[0];
  const float* A     = (const float*)d_in[1];
  const float* W     = (const float*)d_in[2];
  const float* gamma = (const float*)d_in[3];
  const float* beta  = (const float*)d_in[4];
  float* out = (float*)d_out;

  dim3 grid(48 * 16);   // (b,t) x q-tiles of 64 rows; 768 blocks = 3/CU
  sdgcn_mfma<<<grid, 256, 0, stream>>>(X, A, W, gamma, beta, out);
}